// Round 1
// baseline (60.809 us; speedup 1.0000x reference)
//
#include <hip/hip_runtime.h>

#define VOCAB 50257
#define EMBED 128
#define NTOK  (64 * 4096)

// Pass 1: Wt[v][e] = W[e][v] + bias[e]   (LDS-tiled transpose, bias folded in)
// grid.x = ceil(VOCAB/64), block = 256
__global__ void transpose_bias_kernel(const float* __restrict__ W,
                                      const float* __restrict__ bias,
                                      float* __restrict__ Wt) {
    __shared__ float tile[64][EMBED + 1];  // +1 pad breaks bank conflicts
    const int t  = threadIdx.x;
    const int v0 = blockIdx.x * 64;

    // Load W[e][v0+c] -> tile[c][e]; coalesced in v (64 consecutive lanes per row)
#pragma unroll
    for (int it = 0; it < 32; ++it) {
        const int e = (t >> 6) + it * 4;   // 4 rows per iteration
        const int c = t & 63;
        const int v = v0 + c;
        float val = (v < VOCAB) ? W[e * VOCAB + v] : 0.0f;
        tile[c][e] = val;                  // stride 129 floats -> conflict-free
    }
    __syncthreads();

    const float bval = bias[t & (EMBED - 1)];
    // Store Wt[v][e]; coalesced in e (128 consecutive lanes per v)
#pragma unroll
    for (int it = 0; it < 32; ++it) {
        const int c = (t >> 7) + it * 2;   // 2 v-columns per iteration
        const int e = t & (EMBED - 1);
        const int v = v0 + c;
        if (v < VOCAB) Wt[v * EMBED + e] = tile[c][e] + bval;
    }
}

// Pass 2: out[token][:] = Wt[x[token]][:]  — pure coalesced 512B row copy.
// 32 lanes per token, float4 each. total threads = NTOK*32.
__global__ void gather_kernel(const int* __restrict__ x,
                              const float4* __restrict__ Wt,
                              float4* __restrict__ out) {
    const int gid   = blockIdx.x * blockDim.x + threadIdx.x;
    const int token = gid >> 5;
    const int e4    = gid & 31;
    const int idx   = x[token];
    out[token * 32 + e4] = Wt[idx * 32 + e4];
}

// Fallback if workspace is too small: strided column gather (L2-resident W).
__global__ void direct_kernel(const int* __restrict__ x,
                              const float* __restrict__ W,
                              const float* __restrict__ bias,
                              float4* __restrict__ out) {
    const int gid   = blockIdx.x * blockDim.x + threadIdx.x;
    const int token = gid >> 5;
    const int e4    = gid & 31;
    const int idx   = x[token];
    const int e     = e4 * 4;
    float4 r;
    r.x = W[(e + 0) * VOCAB + idx] + bias[e + 0];
    r.y = W[(e + 1) * VOCAB + idx] + bias[e + 1];
    r.z = W[(e + 2) * VOCAB + idx] + bias[e + 2];
    r.w = W[(e + 3) * VOCAB + idx] + bias[e + 3];
    out[token * 32 + e4] = r;
}

extern "C" void kernel_launch(void* const* d_in, const int* in_sizes, int n_in,
                              void* d_out, int out_size, void* d_ws, size_t ws_size,
                              hipStream_t stream) {
    const int*   x    = (const int*)d_in[0];
    const float* W    = (const float*)d_in[1];
    const float* bias = (const float*)d_in[2];
    float*       out  = (float*)d_out;

    const size_t wt_bytes = (size_t)VOCAB * EMBED * sizeof(float);
    const int total   = NTOK * 32;            // 8,388,608 threads
    const int gblocks = total / 256;          // 32768

    if (ws_size >= wt_bytes) {
        float* Wt = (float*)d_ws;
        const int tblocks = (VOCAB + 63) / 64;  // 786
        transpose_bias_kernel<<<tblocks, 256, 0, stream>>>(W, bias, Wt);
        gather_kernel<<<gblocks, 256, 0, stream>>>(x, (const float4*)Wt,
                                                   (float4*)out);
    } else {
        direct_kernel<<<gblocks, 256, 0, stream>>>(x, W, bias, (float4*)out);
    }
}